// Round 5
// baseline (352.058 us; speedup 1.0000x reference)
//
#include <hip/hip_runtime.h>
#include <cstdint>
#include <cstddef>

// ---------------------------------------------------------------------------
// AttentionVAE fused forward — 32x32x16 bf16 MFMA, operand-swapped.
// One block = 32 rows = ONE 32-wide m-tile; 256 threads = 4 waves.
// mfma(W_frag, act_frag): C col = lane&31 = batch row, C reg r = feature
// f = ft*32 + (r&3) + 8*(r>>2) + 4*(lane>>5). Bias folded into weights via a
// constant-1.0 activation column at col K (bias packed at weight row K).
// Decoder: all 4 z-draws in one phase, decoded in 2 passes of 64 rows.
// ---------------------------------------------------------------------------

typedef short short8 __attribute__((ext_vector_type(8)));
typedef float f32x4  __attribute__((ext_vector_type(4)));
typedef float f32x16 __attribute__((ext_vector_type(16)));
typedef unsigned short u16x4 __attribute__((ext_vector_type(4)));
typedef uint32_t u32x2 __attribute__((ext_vector_type(2)));

static constexpr size_t OFF_RECON = 0;
static constexpr size_t OFF_MEAN  = (size_t)262144 * 196;
static constexpr size_t OFF_LOGV  = OFF_MEAN + (size_t)262144 * 8;
static constexpr size_t OFF_ATTN  = OFF_LOGV + (size_t)262144 * 8;
static constexpr size_t OFF_LOSS  = OFF_ATTN + (size_t)262144 * 196;

// ws fragment offsets (bf16 elems). Layer size = FT * KS * 512.
static constexpr int WS_FA1 = 0;       // K196 N98  KS13 FT4
static constexpr int WS_FA2 = 26624;   // K98  N196 KS7  FT7
static constexpr int WS_E1  = 51712;   // K196 N96  KS13 FT3
static constexpr int WS_E2  = 71680;   // K96  N64  KS7  FT2
static constexpr int WS_E3  = 78848;   // K64  N32  KS5  FT1
static constexpr int WS_EMV = 81408;   // K32  N16  KS3  FT1
static constexpr int WS_D1  = 82944;   // K8   N32  KS1  FT1
static constexpr int WS_D2  = 83456;   // K32  N64  KS3  FT2
static constexpr int WS_D3  = 86528;   // K64  N96  KS5  FT3
static constexpr int WS_D4  = 94208;   // K96  N196 KS7  FT7
static constexpr int WS_TOT = 119296;

// LDS layout (ushort units)
static constexpr int XA0 = 0;      // [32][208] x / x_attn (1-slot col 196)
static constexpr int T0  = 6656;   // [32][112] fa hidden  (1-slot col 98)
static constexpr int TA0 = 10240;  // [32][200] a-values
static constexpr int Zo  = 0;      // [128][16] z, 4 draws (1-slot col 8)
static constexpr int D1o = 2048;   // [64][48]  (1-slot col 32)
static constexpr int D2o = 5120;   // [64][80]  (1-slot col 64)
static constexpr int D3o = 10240;  // [64][112] (1-slot col 96)
static constexpr int H1o = 17408;  // [32][112] (1-slot col 96)
static constexpr int H2o = 20992;  // [32][80]  (1-slot col 64)
static constexpr int H3o = 23552;  // [32][48]  (1-slot col 32)
static constexpr int SU_TOT = 25088;

static constexpr int SF_MEAN = 0;    // [32][8]
static constexpr int SF_STD  = 256;  // [32][8]
static constexpr int SF_ATT  = 512;  // [32]
static constexpr int SF_LL   = 544;  // [3][32]
static constexpr int SF_TOT  = 640;

static constexpr unsigned short BF_ONE = 0x3F80;

struct Params {
  const float* x;
  const float* fa_w1; const float* fa_b1; const float* fa_w2; const float* fa_b2;
  const float* e_w1;  const float* e_b1;  const float* e_w2;  const float* e_b2;
  const float* e_w3;  const float* e_b3;  const float* e_wm;  const float* e_bm;
  const float* e_wv;  const float* e_bv;
  const float* d_w1;  const float* d_b1;  const float* d_w2;  const float* d_b2;
  const float* d_w3;  const float* d_b3;  const float* d_w4;  const float* d_b4;
  const float* la_w;  const float* la_b;
  float* out;
  uint32_t key[8];
};

// --------------------------- Threefry-2x32 (JAX) ---------------------------
__host__ __device__ inline void tf2x32(uint32_t k0, uint32_t k1, uint32_t x0, uint32_t x1,
                                       uint32_t& o0, uint32_t& o1)
{
  uint32_t kx = k0 ^ k1 ^ 0x1BD11BDAu;
  uint32_t a = x0 + k0, b = x1 + k1;
#define TF_R(r) { a += b; b = (b << (r)) | (b >> (32 - (r))); b ^= a; }
  TF_R(13) TF_R(15) TF_R(26) TF_R(6)
  a += k1; b += kx + 1u;
  TF_R(17) TF_R(29) TF_R(16) TF_R(24)
  a += kx; b += k0 + 2u;
  TF_R(13) TF_R(15) TF_R(26) TF_R(6)
  a += k0; b += k1 + 3u;
  TF_R(17) TF_R(29) TF_R(16) TF_R(24)
  a += k1; b += kx + 4u;
  TF_R(13) TF_R(15) TF_R(26) TF_R(6)
  a += kx; b += k0 + 5u;
#undef TF_R
  o0 = a; o1 = b;
}

__device__ __forceinline__ float jax_normal(uint32_t k0, uint32_t k1, uint32_t idx)
{
  uint32_t o0, o1;
  tf2x32(k0, k1, 0u, idx, o0, o1);
  uint32_t bits = o0 ^ o1;
  float f = __uint_as_float((bits >> 9) | 0x3f800000u) - 1.0f;
  const float lo = -0.99999994f;
  float u = fmaf(f, 2.0f, lo);
  u = fmaxf(u, lo);
  float w = -log1pf(-u * u);
  float p;
  if (w < 5.0f) {
    w -= 2.5f;
    p = 2.81022636e-08f;
    p = fmaf(p, w, 3.43273939e-07f);
    p = fmaf(p, w, -3.5233877e-06f);
    p = fmaf(p, w, -4.39150654e-06f);
    p = fmaf(p, w, 0.00021858087f);
    p = fmaf(p, w, -0.00125372503f);
    p = fmaf(p, w, -0.00417768164f);
    p = fmaf(p, w, 0.246640727f);
    p = fmaf(p, w, 1.50140941f);
  } else {
    w = sqrtf(w) - 3.0f;
    p = -0.000200214257f;
    p = fmaf(p, w, 0.000100950558f);
    p = fmaf(p, w, 0.00134934322f);
    p = fmaf(p, w, -0.00367342844f);
    p = fmaf(p, w, 0.00573950773f);
    p = fmaf(p, w, -0.0076224613f);
    p = fmaf(p, w, 0.00943887047f);
    p = fmaf(p, w, 1.00167406f);
    p = fmaf(p, w, 2.83297682f);
  }
  return 1.41421356237f * (p * u);
}

// ------------------------------ helpers ------------------------------------
__host__ __device__ __forceinline__ unsigned short f2b(float f) {
  uint32_t u = __float_as_uint(f);
  uint32_t r = u + 0x7fffu + ((u >> 16) & 1u);   // RNE
  return (unsigned short)(r >> 16);
}
__device__ __forceinline__ float b2f(unsigned short hh) {
  return __uint_as_float(((uint32_t)hh) << 16);
}
__device__ __forceinline__ uint32_t cvt_pk(float lo, float hi) {
  uint32_t r;
  asm("v_cvt_pk_bf16_f32 %0, %1, %2" : "=v"(r) : "v"(lo), "v"(hi));
  return r;
}
__device__ __forceinline__ float rcpf(float x) { return __builtin_amdgcn_rcpf(x); }
__device__ __forceinline__ float sigm(float x) { return rcpf(1.0f + __expf(-x)); }
__device__ __forceinline__ float tanh_fast(float x) {
  float xc = fminf(fmaxf(x, -8.0f), 8.0f);
  float t = __expf(2.0f * xc);
  return (t - 1.0f) * rcpf(t + 1.0f);
}

// ------------------------------ weight packer ------------------------------
__global__ void pack_w(Params p, unsigned short* ws)
{
  int e = blockIdx.x * 256 + threadIdx.x;
  if (e >= WS_TOT) return;
  int base, KS, K, N, special = 0;
  const float* src = nullptr; const float* bias = nullptr;
  if (e < WS_FA2)      { base = WS_FA1; KS = 13; K = 196; N = 98;  src = p.fa_w1; bias = p.fa_b1; }
  else if (e < WS_E1)  { base = WS_FA2; KS = 7;  K = 98;  N = 196; src = p.fa_w2; bias = p.fa_b2; }
  else if (e < WS_E2)  { base = WS_E1;  KS = 13; K = 196; N = 96;  src = p.e_w1;  bias = p.e_b1; }
  else if (e < WS_E3)  { base = WS_E2;  KS = 7;  K = 96;  N = 64;  src = p.e_w2;  bias = p.e_b2; }
  else if (e < WS_EMV) { base = WS_E3;  KS = 5;  K = 64;  N = 32;  src = p.e_w3;  bias = p.e_b3; }
  else if (e < WS_D1)  { base = WS_EMV; KS = 3;  K = 32;  N = 16;  special = 1; }
  else if (e < WS_D2)  { base = WS_D1;  KS = 1;  K = 8;   N = 32;  src = p.d_w1;  bias = p.d_b1; }
  else if (e < WS_D3)  { base = WS_D2;  KS = 3;  K = 32;  N = 64;  src = p.d_w2;  bias = p.d_b2; }
  else if (e < WS_D4)  { base = WS_D3;  KS = 5;  K = 64;  N = 96;  src = p.d_w3;  bias = p.d_b3; }
  else                 { base = WS_D4;  KS = 7;  K = 96;  N = 196; src = p.d_w4;  bias = p.d_b4; }
  int local = e - base;
  int j = local & 7, lane = (local >> 3) & 63, t = local >> 9;
  int ksi = t % KS, ft = t / KS;
  int k = ksi * 16 + ((lane >> 5) << 3) + j;
  int n = ft * 32 + (lane & 31);
  float v = 0.f;
  if (n < N) {
    if (k < K)       v = special ? ((n < 8) ? p.e_wm[k * 8 + n] : p.e_wv[k * 8 + (n - 8)])
                                 : src[k * N + n];
    else if (k == K) v = special ? ((n < 8) ? p.e_bm[n] : p.e_bv[n - 8]) : bias[n];
  }
  ws[e] = f2b(v);
}

// ------------------------------ MFMA tile ----------------------------------
// A = weights (lane&31 = feature, k = (lane>>5)*8 + j), prepacked in ws.
// B = activations from LDS (lane&31 = batch row, same k mapping).
template<int KS>
__device__ __forceinline__ f32x16 tile32(const unsigned short* A, int sA,
                                         const unsigned short* W, int ft, int lane)
{
  f32x16 acc = {};
  const unsigned short* ar = A + (lane & 31) * sA + ((lane >> 5) << 3);
  const unsigned short* wp = W + (size_t)(ft * KS * 64 + lane) * 8;
#pragma unroll
  for (int ks = 0; ks < KS; ++ks) {
    short8 bv  = *(const short8*)(ar + ks * 16);
    short8 wv8 = *(const short8*)(wp + ks * 512);
    acc = __builtin_amdgcn_mfma_f32_32x32x16_bf16(wv8, bv, acc, 0, 0, 0);
  }
  return acc;
}

// generic lrelu layer, N multiple of 32 (all runs full)
template<int KS, int MT, int NFT>
__device__ __forceinline__ void layer32(unsigned short* sUb, int aOff, int sA,
                                        int dOff, int sD,
                                        const unsigned short* W, int lane, int wv)
{
  const int m = lane & 31, h = lane >> 5;
  for (int t = wv; t < MT * NFT; t += 4) {
    int mt = (MT == 1) ? 0 : (t & (MT - 1));
    int ft = (MT == 1) ? t : (t >> (MT == 2 ? 1 : 0));
    f32x16 acc = tile32<KS>(sUb + aOff + mt * 32 * sA, sA, W, ft, lane);
    int rr = mt * 32 + m;
#pragma unroll
    for (int g = 0; g < 4; ++g) {
      float v0 = fmaxf(acc[4*g+0], 0.1f * acc[4*g+0]);
      float v1 = fmaxf(acc[4*g+1], 0.1f * acc[4*g+1]);
      float v2 = fmaxf(acc[4*g+2], 0.1f * acc[4*g+2]);
      float v3 = fmaxf(acc[4*g+3], 0.1f * acc[4*g+3]);
      u32x2 pk = { cvt_pk(v0, v1), cvt_pk(v2, v3) };
      *(u32x2*)&sUb[dOff + rr * sD + ft * 32 + 8 * g + 4 * h] = pk;
    }
  }
}

// ------------------------------- the kernel --------------------------------
__launch_bounds__(256, 3)
__global__ void vae_fused(Params p, const unsigned short* ws)
{
  __shared__ unsigned short sU[SU_TOT];
  __shared__ float sF[SF_TOT];
  unsigned short* sUb = sU;

  const int tid = threadIdx.x;
  const int lane = tid & 63;
  const int wv = tid >> 6;
  const int m = lane & 31;
  const int h = lane >> 5;
  const int rb0 = blockIdx.x * 32;

  // ---- init: zero accumulators; load x -> bf16; XA pads ----
  if (tid < 128) sF[SF_ATT + tid] = 0.f;
  for (int idx = tid; idx < 1568; idx += 256) {
    int row = idx / 49, q = idx - row * 49;
    f32x4 xv = *(const f32x4*)(p.x + (size_t)(rb0 + row) * 196 + 4 * q);
    u32x2 pk = { cvt_pk(xv[0], xv[1]), cvt_pk(xv[2], xv[3]) };
    *(u32x2*)&sUb[XA0 + row * 208 + 4 * q] = pk;
  }
  if (tid < 32) {
    unsigned short* r = sUb + XA0 + tid * 208;
    r[196] = BF_ONE; r[197] = 0; r[198] = 0; r[199] = 0;
    u16x4 z4 = {0, 0, 0, 0};
    *(u16x4*)&r[200] = z4; *(u16x4*)&r[204] = z4;
  }
  __syncthreads();

  // ---- FA1: T = tanh(x @ fa_w1 + b), N=98 (1 tile/wave) ----
  {
    int ft = wv;
    f32x16 acc = tile32<13>(sUb + XA0, 208, ws + WS_FA1, ft, lane);
    if (ft < 3) {
#pragma unroll
      for (int g = 0; g < 4; ++g) {
        float v0 = tanh_fast(acc[4*g+0]), v1 = tanh_fast(acc[4*g+1]);
        float v2 = tanh_fast(acc[4*g+2]), v3 = tanh_fast(acc[4*g+3]);
        u32x2 pk = { cvt_pk(v0, v1), cvt_pk(v2, v3) };
        *(u32x2*)&sUb[T0 + m * 112 + ft * 32 + 8 * g + 4 * h] = pk;
      }
    } else if (h == 0) {  // feats 96,97 only
      *(uint32_t*)&sUb[T0 + m * 112 + 96] = cvt_pk(tanh_fast(acc[0]), tanh_fast(acc[1]));
    }
    if (tid < 32) {
      unsigned short* r = sUb + T0 + tid * 112;
      r[98] = BF_ONE; r[99] = 0;
      u16x4 z4 = {0, 0, 0, 0};
      *(u16x4*)&r[100] = z4; *(u16x4*)&r[104] = z4; *(u16x4*)&r[108] = z4;
    }
  }
  __syncthreads();

  // ---- FA2: a = sigmoid(T @ fa_w2 + b) -> TA, row sums -> sF[ATT] ----
  for (int ft = wv; ft < 7; ft += 4) {
    f32x16 acc = tile32<7>(sUb + T0, 112, ws + WS_FA2, ft, lane);
    float s = 0.f;
#pragma unroll
    for (int g = 0; g < 4; ++g) {
      int fb = ft * 32 + 8 * g + 4 * h;
      if (fb <= 192) {
        float a0 = sigm(acc[4*g+0]), a1 = sigm(acc[4*g+1]);
        float a2 = sigm(acc[4*g+2]), a3 = sigm(acc[4*g+3]);
        s += a0 + a1 + a2 + a3;
        u32x2 pk = { cvt_pk(a0, a1), cvt_pk(a2, a3) };
        *(u32x2*)&sUb[TA0 + m * 200 + fb] = pk;
      }
    }
    s += __shfl_xor(s, 32, 64);
    if (lane < 32) atomicAdd(&sF[SF_ATT + m], s);
  }
  __syncthreads();

  // ---- attention apply ----
  for (int idx = tid; idx < 1568; idx += 256) {
    int row = idx / 49, q = idx - row * 49;
    float inv = rcpf(sF[SF_ATT + row] * (1.0f / 196.0f) + 1e-8f);
    u16x4 ah = *(const u16x4*)&sUb[TA0 + row * 200 + 4 * q];
    u16x4 xh = *(const u16x4*)&sUb[XA0 + row * 208 + 4 * q];
    f32x4 aw;
    float xo[4];
#pragma unroll
    for (int i = 0; i < 4; ++i) {
      aw[i] = b2f(ah[i]) * inv;
      xo[i] = b2f(xh[i]) * aw[i];
    }
    __builtin_nontemporal_store(aw, (f32x4*)(p.out + OFF_ATTN + (size_t)(rb0 + row) * 196 + 4 * q));
    u32x2 pk = { cvt_pk(xo[0], xo[1]), cvt_pk(xo[2], xo[3]) };
    *(u32x2*)&sUb[XA0 + row * 208 + 4 * q] = pk;
  }
  __syncthreads();

  // ---- encoder ----
  layer32<13, 1, 3>(sUb, XA0, 208, H1o, 112, ws + WS_E1, lane, wv);
  if (tid < 32) {
    unsigned short* r = sUb + H1o + tid * 112;
    r[96] = BF_ONE; r[97] = 0; r[98] = 0; r[99] = 0;
    u16x4 z4 = {0, 0, 0, 0};
    *(u16x4*)&r[100] = z4; *(u16x4*)&r[104] = z4; *(u16x4*)&r[108] = z4;
  }
  __syncthreads();
  layer32<7, 1, 2>(sUb, H1o, 112, H2o, 80, ws + WS_E2, lane, wv);
  if (tid < 32) {
    unsigned short* r = sUb + H2o + tid * 80;
    r[64] = BF_ONE; r[65] = 0; r[66] = 0; r[67] = 0;
    u16x4 z4 = {0, 0, 0, 0};
    *(u16x4*)&r[68] = z4; *(u16x4*)&r[72] = z4; *(u16x4*)&r[76] = z4;
  }
  __syncthreads();
  layer32<5, 1, 1>(sUb, H2o, 80, H3o, 48, ws + WS_E3, lane, wv);
  if (tid < 32) {
    unsigned short* r = sUb + H3o + tid * 48;
    r[32] = BF_ONE; r[33] = 0; r[34] = 0; r[35] = 0;
    u16x4 z4 = {0, 0, 0, 0};
    *(u16x4*)&r[36] = z4; *(u16x4*)&r[40] = z4; *(u16x4*)&r[44] = z4;
  }
  __syncthreads();

  // ---- mean / logvar (single tile; g0 = mean feats 4h.., g1 = logvar) ----
  if (wv == 0) {
    f32x16 acc = tile32<3>(sUb + H3o, 48, ws + WS_EMV, 0, lane);
    f32x4 mv, lv;
#pragma unroll
    for (int e = 0; e < 4; ++e) { mv[e] = acc[e]; lv[e] = acc[4 + e]; }
#pragma unroll
    for (int e = 0; e < 4; ++e) {
      sF[SF_MEAN + m * 8 + 4 * h + e] = mv[e];
      sF[SF_STD  + m * 8 + 4 * h + e] = __expf(0.5f * lv[e]);
    }
    __builtin_nontemporal_store(mv, (f32x4*)(p.out + OFF_MEAN + (size_t)(rb0 + m) * 8 + 4 * h));
    __builtin_nontemporal_store(lv, (f32x4*)(p.out + OFF_LOGV + (size_t)(rb0 + m) * 8 + 4 * h));
  }
  __syncthreads();

  // ---- all 4 z-draws in one phase ----
  {
    int r = tid >> 1, half = tid & 1;       // r = draw*32 + row
    int draw = r >> 5, row = r & 31;
    float z[4];
#pragma unroll
    for (int e = 0; e < 4; ++e) {
      int jj = 4 * half + e;
      float eps = jax_normal(p.key[2 * draw], p.key[2 * draw + 1],
                             (uint32_t)(rb0 + row) * 8u + (uint32_t)jj);
      z[e] = fmaf(eps, sF[SF_STD + row * 8 + jj], sF[SF_MEAN + row * 8 + jj]);
    }
    u32x2 pk = { cvt_pk(z[0], z[1]), cvt_pk(z[2], z[3]) };
    *(u32x2*)&sUb[Zo + r * 16 + 4 * half] = pk;
    if (tid < 128) {
      u16x4 one4 = {BF_ONE, 0, 0, 0}, z4 = {0, 0, 0, 0};
      *(u16x4*)&sUb[Zo + tid * 16 + 8]  = one4;
      *(u16x4*)&sUb[Zo + tid * 16 + 12] = z4;
    }
  }
  __syncthreads();

  // ---- decoder: 2 passes of 64 rows (draws 2p, 2p+1) ----
#pragma unroll
  for (int pass = 0; pass < 2; ++pass) {
    const int zr = pass * 64;
    layer32<1, 2, 1>(sUb, Zo + zr * 16, 16, D1o, 48, ws + WS_D1, lane, wv);
    if (pass == 0 && tid < 64) {
      unsigned short* r = sUb + D1o + tid * 48;
      r[32] = BF_ONE; r[33] = 0; r[34] = 0; r[35] = 0;
      u16x4 z4 = {0, 0, 0, 0};
      *(u16x4*)&r[36] = z4; *(u16x4*)&r[40] = z4; *(u16x4*)&r[44] = z4;
    }
    __syncthreads();
    layer32<3, 2, 2>(sUb, D1o, 48, D2o, 80, ws + WS_D2, lane, wv);
    if (pass == 0 && tid < 64) {
      unsigned short* r = sUb + D2o + tid * 80;
      r[64] = BF_ONE; r[65] = 0; r[66] = 0; r[67] = 0;
      u16x4 z4 = {0, 0, 0, 0};
      *(u16x4*)&r[68] = z4; *(u16x4*)&r[72] = z4; *(u16x4*)&r[76] = z4;
    }
    __syncthreads();
    layer32<5, 2, 3>(sUb, D2o, 80, D3o, 112, ws + WS_D3, lane, wv);
    if (pass == 0 && tid < 64) {
      unsigned short* r = sUb + D3o + tid * 112;
      r[96] = BF_ONE; r[97] = 0; r[98] = 0; r[99] = 0;
      u16x4 z4 = {0, 0, 0, 0};
      *(u16x4*)&r[100] = z4; *(u16x4*)&r[104] = z4; *(u16x4*)&r[108] = z4;
    }
    __syncthreads();

    // ---- D4 ----
    auto d4_loss = [&](int dp, int ft, int hOff, int sH, float invD, int li) {
      f32x16 acc = tile32<7>(sUb + D3o + dp * 32 * 112, 112, ws + WS_D4, ft, lane);
      float s = 0.f;
#pragma unroll
      for (int g = 0; g < 4; ++g) {
        int fb = ft * 32 + 8 * g + 4 * h;
        u16x4 hh = *(const u16x4*)&sUb[hOff + m * sH + fb];
#pragma unroll
        for (int e = 0; e < 4; ++e) {
          float lr = sigm(acc[4 * g + e]);
          float d = b2f(hh[e]) - lr;
          s = fmaf(d, d, s);
        }
      }
      s += __shfl_xor(s, 32, 64);
      if (lane < 32) atomicAdd(&sF[SF_LL + li * 32 + m], s * invD);
    };

    if (pass == 0) {
      for (int t = wv; t < 10; t += 4) {
        if (t < 7) {  // draw 0: recon
          f32x16 acc = tile32<7>(sUb + D3o, 112, ws + WS_D4, t, lane);
#pragma unroll
          for (int g = 0; g < 4; ++g) {
            int fb = t * 32 + 8 * g + 4 * h;
            if (fb <= 192) {
              f32x4 v;
#pragma unroll
              for (int e = 0; e < 4; ++e) v[e] = sigm(acc[4 * g + e]);
              __builtin_nontemporal_store(v,
                  (f32x4*)(p.out + OFF_RECON + (size_t)(rb0 + m) * 196 + fb));
            }
          }
        } else {      // draw 1: loss vs H1 (96)
          d4_loss(1, t - 7, H1o, 112, 1.0f / 96.0f, 0);
        }
      }
    } else {
      for (int t = wv; t < 3; t += 4) {
        if (t < 2) d4_loss(0, t, H2o, 80, 1.0f / 64.0f, 1);   // draw 2
        else       d4_loss(1, 0, H3o, 48, 1.0f / 32.0f, 2);   // draw 3
      }
    }
    __syncthreads();
  }

  // ---- layer attention + weighted loss ----
  if (tid < 32) {
    int r = tid;
    float l0 = sF[SF_LL + r], l1 = sF[SF_LL + 32 + r], l2 = sF[SF_LL + 64 + r];
    float lg[3];
#pragma unroll
    for (int i = 0; i < 3; ++i)
      lg[i] = p.la_b[i] + l0 * p.la_w[0 * 3 + i] + l1 * p.la_w[1 * 3 + i] + l2 * p.la_w[2 * 3 + i];
    float mx = fmaxf(lg[0], fmaxf(lg[1], lg[2]));
    float e0 = __expf(lg[0] - mx), e1 = __expf(lg[1] - mx), e2 = __expf(lg[2] - mx);
    float inv = rcpf(e0 + e1 + e2);
    float wll = (l0 * e0 + l1 * e1 + l2 * e2) * inv;
#pragma unroll
    for (int mm = 1; mm <= 16; mm <<= 1) wll += __shfl_xor(wll, mm, 64);
    if (tid == 0) atomicAdd(p.out + OFF_LOSS, wll * (1.0f / 262144.0f));
  }
}

// ------------------------------ host launcher ------------------------------
extern "C" void kernel_launch(void* const* d_in, const int* in_sizes, int n_in,
                              void* d_out, int out_size, void* d_ws, size_t ws_size,
                              hipStream_t stream)
{
  (void)in_sizes; (void)n_in; (void)ws_size; (void)out_size;
  Params p;
  p.x     = (const float*)d_in[0];
  p.fa_w1 = (const float*)d_in[1];  p.fa_b1 = (const float*)d_in[2];
  p.fa_w2 = (const float*)d_in[3];  p.fa_b2 = (const float*)d_in[4];
  p.e_w1  = (const float*)d_in[5];  p.e_b1  = (const float*)d_in[6];
  p.e_w2  = (const float*)d_in[7];  p.e_b2  = (const float*)d_in[8];
  p.e_w3  = (const float*)d_in[9];  p.e_b3  = (const float*)d_in[10];
  p.e_wm  = (const float*)d_in[11]; p.e_bm  = (const float*)d_in[12];
  p.e_wv  = (const float*)d_in[13]; p.e_bv  = (const float*)d_in[14];
  p.d_w1  = (const float*)d_in[15]; p.d_b1  = (const float*)d_in[16];
  p.d_w2  = (const float*)d_in[17]; p.d_b2  = (const float*)d_in[18];
  p.d_w3  = (const float*)d_in[19]; p.d_b3  = (const float*)d_in[20];
  p.d_w4  = (const float*)d_in[21]; p.d_b4  = (const float*)d_in[22];
  p.la_w  = (const float*)d_in[23]; p.la_b  = (const float*)d_in[24];
  p.out   = (float*)d_out;

  for (uint32_t j = 0; j < 4; ++j) {
    uint32_t o0, o1;
    tf2x32(0u, 42u, 0u, j, o0, o1);
    p.key[2 * j] = o0; p.key[2 * j + 1] = o1;
  }

  hipMemsetAsync((char*)d_out + OFF_LOSS * sizeof(float), 0, sizeof(float), stream);

  unsigned short* ws = (unsigned short*)d_ws;
  pack_w<<<(WS_TOT + 255) / 256, 256, 0, stream>>>(p, ws);
  vae_fused<<<262144 / 32, 256, 0, stream>>>(p, ws);
}